// Round 7
// baseline (179.609 us; speedup 1.0000x reference)
//
#include <hip/hip_runtime.h>

#define R 192
#define BATCH 1024
#define NWORDS (R * 6)          // 192 rows x 6 u32 bit-words
#define MAIN_BLOCKS (2 * BATCH) // 2 stripes x 1024 batches

// ws layout (floats):
//   ws[0]=overlap  ws[1]=adj  ws[2]=mseP  ws[3]=mseS  ws[4]=ticket(u32)  [zeroed by prep]
//   ws[8 ..]      : u32 mask[192][6], triu-baked: bit j set iff j>i && adj[i][j]>0
#define MASK_OFF_W 8

__global__ __launch_bounds__(256) void prep_kernel(
    const int* __restrict__ adj, float* __restrict__ ws)
{
    unsigned int* bits = (unsigned int*)(ws + MASK_OFF_W);
    const int e = blockIdx.x * 256 + threadIdx.x;   // 0 .. R*R-1
    if (e < 8) ws[e] = 0.0f;
    if (e >= R * R) return;
    const int i = e / R;
    const int j = e - i * R;
    const unsigned long long m = __ballot((adj[e] > 0) && (j > i));
    const int lane = e & 63;
    if (lane == 0)  bits[e >> 5] = (unsigned int)m;
    if (lane == 32) bits[e >> 5] = (unsigned int)(m >> 32);
}

// NOTE: no min-waves arg — R6's (256,6) forced VGPR=16 and serialized the
// kernel on operand-reload latency (116 us, VALUBusy 15%). Let the allocator
// keep operands in registers.
__global__ __launch_bounds__(256) void main_kernel(
    const float* __restrict__ pos, const float* __restrict__ siz,
    const float* __restrict__ tpos, const float* __restrict__ tsiz,
    float* __restrict__ ws, float* __restrict__ out)
{
    __shared__ float4 room[R];          // x, y, x+w, y+h
    __shared__ float2 ctr2[R];          // (2*cx, 2*cy)
    __shared__ unsigned int smask[NWORDS];
    __shared__ float wsum[4][4];
    __shared__ int is_last;

    const int s   = blockIdx.x;         // 0/1 stripe
    const int b   = blockIdx.y;
    const int tid = threadIdx.x;

    const unsigned int* gmask = (const unsigned int*)(ws + MASK_OFF_W);

    float mp = 0.0f, ms = 0.0f;

    if (tid < R) {
        const float2 p  = ((const float2*)pos)[(size_t)b * R + tid];
        const float2 sz = ((const float2*)siz)[(size_t)b * R + tid];
        const float xw = p.x + sz.x;
        const float yh = p.y + sz.y;
        room[tid] = make_float4(p.x, p.y, xw, yh);
        ctr2[tid] = make_float2(p.x + xw, p.y + yh);
        if (s == 0) {
            const float2 tp = ((const float2*)tpos)[(size_t)b * R + tid];
            const float2 ts = ((const float2*)tsiz)[(size_t)b * R + tid];
            float dpx = p.x - tp.x, dpy = p.y - tp.y;
            float dsx = sz.x - ts.x, dsy = sz.y - ts.y;
            mp = dpx * dpx + dpy * dpy;
            ms = dsx * dsx + dsy * dsy;
        }
    }
    for (int w = tid; w < NWORDS; w += 256) smask[w] = gmask[w];
    __syncthreads();

    const int li = tid >> 4;            // 0..15
    const int lj = tid & 15;            // 0..15
    float ov = 0.0f, ad = 0.0f;

    for (int ti = 0; ti < 12; ++ti) {
        const int i = ti * 16 + li;
        const float4 ri = room[i];
        const float2 ci = ctr2[i];
        const unsigned int* rowbits = &smask[i * 6];

        int tj = ti + 1 + s;
        // unrolled-by-2: loads for both slots issued before either is consumed
        for (; tj + 2 < 12; tj += 4) {
            const int j0 = tj * 16 + lj;
            const int j1 = (tj + 2) * 16 + lj;
            const float4 rj0 = room[j0];
            const float2 cj0 = ctr2[j0];
            const float4 rj1 = room[j1];
            const float2 cj1 = ctr2[j1];
            const unsigned int mw0 = rowbits[tj >> 1];
            const unsigned int mw1 = rowbits[(tj + 2) >> 1];

            {
                float ow = fminf(ri.z, rj0.z) - fmaxf(ri.x, rj0.x);
                float oh = fminf(ri.w, rj0.w) - fmaxf(ri.y, rj0.y);
                ov = fmaf(fmaxf(ow, 0.0f), fmaxf(oh, 0.0f), ov);
                const unsigned int bit = (mw0 >> (((tj & 1) << 4) + lj)) & 1u;
                float dx = ci.x - cj0.x;
                float dy = ci.y - cj0.y;
                float r2 = __builtin_amdgcn_sqrtf(fmaf(dx, dx, dy * dy));
                ad = fmaf(bit ? 0.5f : 0.0f, r2, ad);
            }
            {
                float ow = fminf(ri.z, rj1.z) - fmaxf(ri.x, rj1.x);
                float oh = fminf(ri.w, rj1.w) - fmaxf(ri.y, rj1.y);
                ov = fmaf(fmaxf(ow, 0.0f), fmaxf(oh, 0.0f), ov);
                const unsigned int bit = (mw1 >> (((tj & 1) << 4) + lj)) & 1u;
                float dx = ci.x - cj1.x;
                float dy = ci.y - cj1.y;
                float r2 = __builtin_amdgcn_sqrtf(fmaf(dx, dx, dy * dy));
                ad = fmaf(bit ? 0.5f : 0.0f, r2, ad);
            }
        }
        for (; tj < 12; tj += 2) {
            const int j = tj * 16 + lj;
            const float4 rj = room[j];
            const float2 cj = ctr2[j];
            const unsigned int mw = rowbits[tj >> 1];
            float ow = fminf(ri.z, rj.z) - fmaxf(ri.x, rj.x);
            float oh = fminf(ri.w, rj.w) - fmaxf(ri.y, rj.y);
            ov = fmaf(fmaxf(ow, 0.0f), fmaxf(oh, 0.0f), ov);
            const unsigned int bit = (mw >> (((tj & 1) << 4) + lj)) & 1u;
            float dx = ci.x - cj.x;
            float dy = ci.y - cj.y;
            float r2 = __builtin_amdgcn_sqrtf(fmaf(dx, dx, dy * dy));
            ad = fmaf(bit ? 0.5f : 0.0f, r2, ad);
        }

        if (s == 1) {   // diagonal tile: tj == ti; mask already 0 for j<=i
            const int j = ti * 16 + lj;
            const float4 rj = room[j];
            const float2 cj = ctr2[j];
            const unsigned int mw = rowbits[ti >> 1];
            float ow = fminf(ri.z, rj.z) - fmaxf(ri.x, rj.x);
            float oh = fminf(ri.w, rj.w) - fmaxf(ri.y, rj.y);
            float area = fmaxf(ow, 0.0f) * fmaxf(oh, 0.0f);
            ov += (i < j) ? area : 0.0f;
            const unsigned int bit = (mw >> (((ti & 1) << 4) + lj)) & 1u;
            float dx = ci.x - cj.x;
            float dy = ci.y - cj.y;
            float r2 = __builtin_amdgcn_sqrtf(fmaf(dx, dx, dy * dy));
            ad = fmaf(bit ? 0.5f : 0.0f, r2, ad);
        }
    }

    for (int off = 32; off > 0; off >>= 1) {
        ov += __shfl_down(ov, off);
        ad += __shfl_down(ad, off);
        mp += __shfl_down(mp, off);
        ms += __shfl_down(ms, off);
    }
    const int wid = tid >> 6, lane = tid & 63;
    if (lane == 0) {
        wsum[wid][0] = ov; wsum[wid][1] = ad;
        wsum[wid][2] = mp; wsum[wid][3] = ms;
    }
    __syncthreads();
    if (tid == 0) {
        atomicAdd(&ws[0], wsum[0][0] + wsum[1][0] + wsum[2][0] + wsum[3][0]);
        atomicAdd(&ws[1], wsum[0][1] + wsum[1][1] + wsum[2][1] + wsum[3][1]);
        if (s == 0) {
            atomicAdd(&ws[2], wsum[0][2] + wsum[1][2] + wsum[2][2] + wsum[3][2]);
            atomicAdd(&ws[3], wsum[0][3] + wsum[1][3] + wsum[2][3] + wsum[3][3]);
        }
        __threadfence();
        unsigned int old = atomicAdd((unsigned int*)(ws + 4), 1u);
        is_last = (old == (unsigned int)(MAIN_BLOCKS - 1)) ? 1 : 0;
    }
    __syncthreads();

    if (is_last && tid == 0) {
        float ovT  = atomicAdd(&ws[0], 0.0f);
        float adT  = atomicAdd(&ws[1], 0.0f);
        float mseP = atomicAdd(&ws[2], 0.0f);
        float mseS = atomicAdd(&ws[3], 0.0f);
        const float invN = 1.0f / (float)(BATCH * R * 2);
        const float invB = 1.0f / (float)BATCH;
        float pos_loss  = mseP * invN;
        float size_loss = mseS * invN;
        float overlap   = ovT * invB;
        float adjl      = adT * invB;
        out[0] = pos_loss + size_loss + 0.5f * overlap + 0.3f * adjl;
        out[1] = pos_loss;
        out[2] = size_loss;
        out[3] = overlap;
        out[4] = adjl;
    }
}

extern "C" void kernel_launch(void* const* d_in, const int* in_sizes, int n_in,
                              void* d_out, int out_size, void* d_ws, size_t ws_size,
                              hipStream_t stream) {
    const float* pos  = (const float*)d_in[0];
    const float* siz  = (const float*)d_in[1];
    const float* tpos = (const float*)d_in[2];
    const float* tsiz = (const float*)d_in[3];
    const int*   adj  = (const int*)d_in[4];
    float* ws  = (float*)d_ws;
    float* out = (float*)d_out;

    hipLaunchKernelGGL(prep_kernel, dim3((R * R + 255) / 256), dim3(256), 0, stream,
                       adj, ws);
    hipLaunchKernelGGL(main_kernel, dim3(2, BATCH), dim3(256), 0, stream,
                       pos, siz, tpos, tsiz, ws, out);
}